// Round 24
// baseline (146.306 us; speedup 1.0000x reference)
//
#include <hip/hip_runtime.h>

// B=8, N=2048, D_IN=D_OUT=512. out fp32 [8,2048,512].
// BIG-WS layout (needs >=136052736 B): P@0 (64M), Qb@64M, Kb@80M, Vt@96M,
// Wt@128M, lbuf@129.5M. FALLBACK: Qb@16M, Kb@32M, Vt@48M, Wt@64M.
// Round-24 delta vs round-23 (verified 141.3us): k_pv dh-split 4 -> 8 way
// (grid 1024 = 4 blocks/CU; pv was grid-capped at 2 with VGPR 48-80 headroom).
// dh encoded in blk bits 3-5 so all 8 same-(b,qt) blocks (sharing a 512KB P
// slice) are dispatch-adjacent on the SAME XCD -> P duplication is L2-served.
// Pure data-parallel reshape: no sync-structure change (round-22 lesson).

typedef __bf16 bf16x8 __attribute__((ext_vector_type(8)));
typedef float f32x4 __attribute__((ext_vector_type(4)));
typedef float f32x16 __attribute__((ext_vector_type(16)));

#define AS1G __attribute__((address_space(1)))
#define AS3L __attribute__((address_space(3)))

__device__ __forceinline__ void gload16(const void* g, void* l) {
  __builtin_amdgcn_global_load_lds((const AS1G void*)g, (AS3L void*)l, 16, 0, 0);
}

// ---------------- W [d][e] fp32 -> Wt [z][e][d] bf16 ----------------
__global__ __launch_bounds__(256) void k_wt(const float* __restrict__ Wq, const float* __restrict__ Wk,
                                            const float* __restrict__ Wv, __bf16* __restrict__ Wt) {
  __shared__ float t[32][33];
  int z = blockIdx.z;
  const float* W = (z == 0) ? Wq : (z == 1 ? Wk : Wv);
  int r0 = blockIdx.y * 32, c0 = blockIdx.x * 32;
  int tr = threadIdx.x >> 5, tc = threadIdx.x & 31;
#pragma unroll
  for (int p = 0; p < 4; p++)
    t[tr + p * 8][tc] = W[(size_t)(r0 + tr + p * 8) * 512 + c0 + tc];
  __syncthreads();
#pragma unroll
  for (int p = 0; p < 4; p++)
    Wt[(size_t)z * 262144 + (size_t)(c0 + tr + p * 8) * 512 + r0 + tc] = (__bf16)t[tc][tr + p * 8];
}

// ---------------- fused QKV GEMM (x fp32 read + convert fused, round-21-verified) ----------------
__global__ __launch_bounds__(256) void k_gemm(const float* __restrict__ x, const __bf16* __restrict__ Wt,
                                              const float* __restrict__ bq, const float* __restrict__ bk,
                                              const float* __restrict__ bv,
                                              __bf16* __restrict__ Qb, __bf16* __restrict__ Kb,
                                              __bf16* __restrict__ Vt) {
  __shared__ float sA[128 * 64];
  __shared__ __bf16 sB[128 * 64];
  int blk = blockIdx.x;
  int xcd = blk & 7;
  int within = blk >> 3;
  int ph = within / 12;
  int j = within - ph * 12;
  int m0 = (ph * 8 + xcd) * 128;  // XCD panel clustering (round-19: FETCH 99.9->33MB)
  int e0 = (j & 3) * 128;
  int z = j >> 2;
  int tid = threadIdx.x, w = tid >> 6, l = tid & 63;
  int lr = l & 15, lg = l >> 4;
  int wm = (w & 1) * 64, wn = (w >> 1) * 64;
  const float* bias = (z == 0) ? bq : (z == 1 ? bk : bv);
  const __bf16* Wz = Wt + (size_t)z * 262144;

  float bval[4];
#pragma unroll
  for (int fn = 0; fn < 4; fn++) bval[fn] = bias[e0 + wn + fn * 16 + lr];

  f32x4 zero4 = {0.f, 0.f, 0.f, 0.f};
  f32x4 acc[4][4];
#pragma unroll
  for (int fm = 0; fm < 4; fm++)
#pragma unroll
    for (int fn = 0; fn < 4; fn++) acc[fm][fn] = zero4;

#pragma unroll 1
  for (int kt = 0; kt < 8; kt++) {
#pragma unroll
    for (int ii = 0; ii < 8; ii++) {
      int R0 = w * 32 + ii * 4;
      int row = R0 + (l >> 4);
      int cs = (l & 15) ^ ((2 * (row >> 1)) & 15);
      gload16(x + (size_t)(m0 + row) * 512 + kt * 64 + cs * 4, sA + R0 * 64);
    }
#pragma unroll
    for (int ii = 0; ii < 4; ii++) {
      int rt = (w * 4 + ii) * 8 + (l >> 3);
      int sw = ((l & 7) ^ (l >> 3)) << 3;
      gload16(Wz + (size_t)(e0 + rt) * 512 + kt * 64 + sw, sB + (w * 4 + ii) * 512);
    }
    __syncthreads();
#pragma unroll
    for (int kc = 0; kc < 2; kc++) {
      bf16x8 af[4], bfr[4];
#pragma unroll
      for (int f = 0; f < 4; f++) {
        int ra = wm + f * 16 + lr;
        int m = kc * 4 + lg;
        int pos = 2 * (m ^ ((ra >> 1) & 7));
        const float* pA = sA + ra * 64 + pos * 4;
        f32x4 a0 = *(const f32x4*)(pA);
        f32x4 a1 = *(const f32x4*)(pA + 4);
        bf16x8 av;
        av[0] = (__bf16)a0[0]; av[1] = (__bf16)a0[1]; av[2] = (__bf16)a0[2]; av[3] = (__bf16)a0[3];
        av[4] = (__bf16)a1[0]; av[5] = (__bf16)a1[1]; av[6] = (__bf16)a1[2]; av[7] = (__bf16)a1[3];
        af[f] = av;
        int rb = wn + f * 16 + lr;
        bfr[f] = *(const bf16x8*)(sB + rb * 64 + (((kc * 4 + lg) ^ (rb & 7)) << 3));
      }
#pragma unroll
      for (int fm = 0; fm < 4; fm++)
#pragma unroll
        for (int fn = 0; fn < 4; fn++)
          acc[fm][fn] = __builtin_amdgcn_mfma_f32_16x16x32_bf16(af[fm], bfr[fn], acc[fm][fn], 0, 0, 0);
    }
    __syncthreads();
  }

  if (z == 2) {
    int bb = m0 >> 11;
#pragma unroll
    for (int fm = 0; fm < 4; fm++) {
      int nl = (m0 & 2047) + wm + fm * 16 + lg * 4;
#pragma unroll
      for (int fn = 0; fn < 4; fn++) {
        alignas(8) __bf16 tmp[4];
#pragma unroll
        for (int r = 0; r < 4; r++) tmp[r] = (__bf16)(acc[fm][fn][r] + bval[fn]);
        *(float2*)(Vt + (size_t)bb * 1048576 + (size_t)(e0 + wn + fn * 16 + lr) * 2048 + nl) =
            *(float2*)tmp;
      }
    }
  } else {
    __bf16* dst = (z == 0) ? Qb : Kb;
    const float qmul = (z == 0) ? (1.4426950408889634f * 0.044194173824159216f) : 1.0f;
#pragma unroll
    for (int fm = 0; fm < 4; fm++)
#pragma unroll
      for (int fn = 0; fn < 4; fn++)
#pragma unroll
        for (int r = 0; r < 4; r++) {
          float v = (acc[fm][fn][r] + bval[fn]) * qmul;
          dst[(size_t)(m0 + wm + fm * 16 + lg * 4 + r) * 512 + e0 + wn + fn * 16 + lr] = (__bf16)v;
        }
  }
}

// ================= TWO-PASS PATH (big ws) =================
// No-max softmax (|s|<=36): P-tiles directly summable. QK once, P (bf16
// A-frags, 64MB) in ws, PV reads P from global. Both 32x32x16 MFMA.
// P byte addr: ((((b*16+qt)*64 + kvt)*2 + s2)*256 + tid)*16.

// k_qk: grid 512 = 8b x 16qt x 4kvh. 4 waves x 32 q-rows; kv quarter (512), 16 iters.
__global__ __launch_bounds__(256, 1) void k_qk(const __bf16* __restrict__ Qb, const __bf16* __restrict__ Kb,
                                               __bf16* __restrict__ P, float* __restrict__ lbuf) {
  __shared__ __bf16 sK[2][32 * 512];  // dbuf, XOR-8 16B-chunk swizzle per row

  int tid = threadIdx.x;
  int w = tid >> 6, l = tid & 63;
  int q32 = l & 31, hi = l >> 5;

  int blk = blockIdx.x;
  int b = blk & 7;
  int qt = (blk >> 3) & 15;
  int kvh = blk >> 7;

  const __bf16* Kbase = Kb + (size_t)b * 2048 * 512 + (size_t)kvh * 512 * 512;

  bf16x8 qf[32];
  const __bf16* qrow = Qb + (size_t)(b * 2048 + qt * 128 + w * 32 + q32) * 512 + hi * 8;
#pragma unroll
  for (int ks = 0; ks < 32; ks++) qf[ks] = *(const bf16x8*)(qrow + ks * 16);

  float l_run = 0.f;

#pragma unroll
  for (int i = 0; i < 8; i++) {
    int row = w * 8 + i;
    gload16(Kbase + (size_t)row * 512 + ((l ^ i) << 3), sK[0] + row * 512);
  }

#pragma unroll 1
  for (int it = 0; it < 16; it++) {
    int cur = it & 1;
    __syncthreads();

    if (it < 15) {
#pragma unroll
      for (int i = 0; i < 8; i++) {
        int row = w * 8 + i;
        gload16(Kbase + (size_t)((it + 1) * 32 + row) * 512 + ((l ^ i) << 3),
                sK[cur ^ 1] + row * 512);
      }
    }

    f32x16 s;
#pragma unroll
    for (int r = 0; r < 16; r++) s[r] = 0.f;
    __builtin_amdgcn_s_setprio(1);
#pragma unroll
    for (int ks = 0; ks < 32; ks++) {
      int c0 = 2 * ks + hi;
      bf16x8 kf = *(const bf16x8*)(sK[cur] + q32 * 512 + ((c0 ^ (q32 & 7)) << 3));
      s = __builtin_amdgcn_mfma_f32_32x32x16_bf16(kf, qf[ks], s, 0, 0, 0);
    }
    __builtin_amdgcn_s_setprio(0);

    union Pk { unsigned u; __bf16 h[2]; };
    unsigned pk[4][2];
    float ps = 0.f;
#pragma unroll
    for (int g = 0; g < 4; g++) {
      float p0 = exp2f(s[4 * g + 0]), p1 = exp2f(s[4 * g + 1]);
      float p2 = exp2f(s[4 * g + 2]), p3 = exp2f(s[4 * g + 3]);
      ps += (p0 + p1) + (p2 + p3);
      Pk t0; t0.h[0] = (__bf16)p0; t0.h[1] = (__bf16)p1; pk[g][0] = t0.u;
      Pk t1; t1.h[0] = (__bf16)p2; t1.h[1] = (__bf16)p3; pk[g][1] = t1.u;
    }
    l_run += ps;

    int kvt = kvh * 16 + it;
    size_t pbase = (((size_t)(b * 16 + qt) * 64 + kvt) * 2) * 256 + tid;
#pragma unroll
    for (int s2 = 0; s2 < 2; s2++) {
      unsigned snd0 = hi ? pk[2 * s2][0] : pk[2 * s2 + 1][0];
      unsigned snd1 = hi ? pk[2 * s2][1] : pk[2 * s2 + 1][1];
      unsigned rc0 = __shfl_xor(snd0, 32);
      unsigned rc1 = __shfl_xor(snd1, 32);
      union Fr { unsigned u[4]; f32x4 f; } fu;
      fu.u[0] = hi ? rc0 : pk[2 * s2][0];
      fu.u[1] = hi ? rc1 : pk[2 * s2][1];
      fu.u[2] = hi ? pk[2 * s2 + 1][0] : rc0;
      fu.u[3] = hi ? pk[2 * s2 + 1][1] : rc1;
      ((f32x4*)P)[pbase + (size_t)s2 * 256] = fu.f;
    }
  }

  l_run += __shfl_xor(l_run, 32);
  if (hi == 0)
    lbuf[(size_t)(b * 4 + kvh) * 2048 + qt * 128 + w * 32 + q32] = l_run;
}

// k_pv: grid 1024 = 8b x 8dh x 16qt (dh in bits 3-5: same-(b,qt) blocks adjacent,
// same XCD -> shared 512KB P slice L2-resident). 4 waves x 32 q x 64 d; 64 kv-tiles.
__global__ __launch_bounds__(256, 2) void k_pv(const __bf16* __restrict__ P, const __bf16* __restrict__ Vt,
                                               const float* __restrict__ lbuf, float* __restrict__ out) {
  __shared__ __bf16 sV[2][32 * 64];  // paired d-rows rr=(d-d0)>>1 in [0,32), XOR-swz chunks

  int tid = threadIdx.x;
  int w = tid >> 6, l = tid & 63;
  int q32 = l & 31, hi = l >> 5;

  int blk = blockIdx.x;
  int b = blk & 7;
  int dh = (blk >> 3) & 7;
  int qt = blk >> 6;
  int d0 = dh * 64;

  const __bf16* Vbase = Vt + (size_t)b * 512 * 2048 + (size_t)d0 * 2048;

  f32x16 o[2];
#pragma unroll
  for (int dt = 0; dt < 2; dt++)
#pragma unroll
    for (int r = 0; r < 16; r++) o[dt][r] = 0.f;

  // prologue: stage V(0) -> sV[0]; 1 instr/wave (8 paired rows x 128B)
  {
    int rr = w * 8 + (l >> 3);
    int cl = (l & 7) ^ (l >> 3);
    gload16(Vbase + (size_t)(2 * rr + (cl >> 2)) * 2048 + ((cl & 3) << 3), sV[0] + w * 512);
  }

  size_t pbase0 = ((size_t)(b * 16 + qt) * 64) * 2 * 256 + tid;
  union Fr { f32x4 f; bf16x8 h; };
  Fr u0, u1, n0, n1, m0, m1;
  u0.f = ((const f32x4*)P)[pbase0];
  u1.f = ((const f32x4*)P)[pbase0 + 256];
  n0.f = ((const f32x4*)P)[pbase0 + 512];
  n1.f = ((const f32x4*)P)[pbase0 + 512 + 256];

#pragma unroll 1
  for (int kvt = 0; kvt < 64; kvt++) {
    int cur = kvt & 1;
    __syncthreads();  // V(kvt) landed; reads of sV[cur^1] done block-wide

    if (kvt < 63) {
      int rr = w * 8 + (l >> 3);
      int cl = (l & 7) ^ (l >> 3);
      gload16(Vbase + (size_t)(2 * rr + (cl >> 2)) * 2048 + (kvt + 1) * 32 + ((cl & 3) << 3),
              sV[cur ^ 1] + w * 512);
    }
    if (kvt < 62) {
      m0.f = ((const f32x4*)P)[pbase0 + (size_t)(kvt + 2) * 512];
      m1.f = ((const f32x4*)P)[pbase0 + (size_t)(kvt + 2) * 512 + 256];
    }

    // O += P * V (round-11-verified B-frag formula; rr in [0,32), same rr&7 swz)
    __builtin_amdgcn_s_setprio(1);
#pragma unroll
    for (int dt = 0; dt < 2; dt++) {
      int dd = dt * 32 + q32;
      int rr = dd >> 1;
      int cp0 = (((dd & 1) << 2) | hi) ^ (rr & 7);
      bf16x8 vf0 = *(const bf16x8*)(sV[cur] + rr * 64 + (cp0 << 3));
      o[dt] = __builtin_amdgcn_mfma_f32_32x32x16_bf16(u0.h, vf0, o[dt], 0, 0, 0);
      int cp1 = (((dd & 1) << 2) | (2 + hi)) ^ (rr & 7);
      bf16x8 vf1 = *(const bf16x8*)(sV[cur] + rr * 64 + (cp1 << 3));
      o[dt] = __builtin_amdgcn_mfma_f32_32x32x16_bf16(u1.h, vf1, o[dt], 0, 0, 0);
    }
    __builtin_amdgcn_s_setprio(0);
    u0 = n0; u1 = n1;  // static rotation (rule #20)
    n0 = m0; n1 = m1;
  }

  float L = 0.f;
  const float* lb = lbuf + (size_t)b * 4 * 2048 + qt * 128 + w * 32 + q32;
#pragma unroll
  for (int kvh = 0; kvh < 4; kvh++) L += lb[(size_t)kvh * 2048];

  float* obase = out + (size_t)(b * 2048 + qt * 128 + w * 32) * 512 + d0;
#pragma unroll
  for (int r = 0; r < 16; r++) {
    int q = (r & 3) + 8 * (r >> 2) + 4 * hi;
    float iv = 1.0f / __shfl(L, q);
#pragma unroll
    for (int dt = 0; dt < 2; dt++)
      obase[(size_t)q * 512 + dt * 32 + q32] = o[dt][r] * iv;
  }
}

// ================= FALLBACK (round-14 k_fa) =================
__global__ __launch_bounds__(256, 2) void k_fa(const __bf16* __restrict__ Qb, const __bf16* __restrict__ Kb,
                                               const __bf16* __restrict__ Vt, float* __restrict__ out) {
  __shared__ __bf16 sK[32 * 512];
  __shared__ __bf16 sV[2][128 * 64];

  int tid = threadIdx.x;
  int w = tid >> 6, l = tid & 63;
  int lr = l & 15, lg = l >> 4;

  int blk = blockIdx.x;
  int b = blk & 7;
  int q0 = ((blk >> 3) & 31) * 64;
  int d0 = (blk >> 8) * 256;

  const __bf16* Kbase = Kb + (size_t)b * 2048 * 512;
  const __bf16* Vbase = Vt + (size_t)b * 512 * 2048 + (size_t)d0 * 2048;

  bf16x8 qf[16];
  const __bf16* qrow = Qb + (size_t)(b * 2048 + q0 + w * 16 + lr) * 512;
#pragma unroll
  for (int dk = 0; dk < 16; dk++) qf[dk] = *(const bf16x8*)(qrow + dk * 32 + lg * 8);

  f32x4 zero4 = {0.f, 0.f, 0.f, 0.f};
  f32x4 o[16];
#pragma unroll
  for (int dj = 0; dj < 16; dj++) o[dj] = zero4;
  float l_run = 0.f;

#pragma unroll
  for (int i = 0; i < 8; i++) {
    int row = w * 8 + i;
    gload16(Kbase + (size_t)row * 512 + ((l ^ i) << 3), sK + row * 512);
  }
#pragma unroll
  for (int i = 0; i < 4; i++) {
    int rr = (w * 4 + i) * 8 + (l >> 3);
    int cl = (l & 7) ^ (l >> 3);
    gload16(Vbase + (size_t)(2 * rr + (cl >> 2)) * 2048 + ((cl & 3) << 3),
            sV[0] + (w * 4 + i) * 512);
  }

#pragma unroll 1
  for (int it = 0; it < 64; it++) {
    int cur = it & 1;
    __syncthreads();

    f32x4 s[2] = {zero4, zero4};
    __builtin_amdgcn_s_setprio(1);
#pragma unroll
    for (int dk = 0; dk < 16; dk++) {
#pragma unroll
      for (int j = 0; j < 2; j++) {
        int row = j * 16 + lr;
        bf16x8 kf = *(const bf16x8*)(sK + row * 512 + (((dk * 4 + lg) ^ (lr & 7)) << 3));
        s[j] = __builtin_amdgcn_mfma_f32_16x16x32_bf16(kf, qf[dk], s[j], 0, 0, 0);
      }
    }
    __builtin_amdgcn_s_setprio(0);
    __syncthreads();

    if (it < 63) {
      int kvn = (it + 1) * 32;
#pragma unroll
      for (int i = 0; i < 8; i++) {
        int row = w * 8 + i;
        gload16(Kbase + (size_t)(kvn + row) * 512 + ((l ^ i) << 3), sK + row * 512);
      }
#pragma unroll
      for (int i = 0; i < 4; i++) {
        int rr = (w * 4 + i) * 8 + (l >> 3);
        int cl = (l & 7) ^ (l >> 3);
        gload16(Vbase + (size_t)(2 * rr + (cl >> 2)) * 2048 + kvn + ((cl & 3) << 3),
                sV[cur ^ 1] + (w * 4 + i) * 512);
      }
    }

    float p00 = exp2f(s[0][0]), p01 = exp2f(s[0][1]);
    float p02 = exp2f(s[0][2]), p03 = exp2f(s[0][3]);
    float p10 = exp2f(s[1][0]), p11 = exp2f(s[1][1]);
    float p12 = exp2f(s[1][2]), p13 = exp2f(s[1][3]);
    l_run += ((p00 + p01) + (p02 + p03)) + ((p10 + p11) + (p12 + p13));

    union Pk { unsigned u; __bf16 h[2]; };
    Pk A0, A1, B0, B1;
    A0.h[0] = (__bf16)p00; A0.h[1] = (__bf16)p01;
    A1.h[0] = (__bf16)p02; A1.h[1] = (__bf16)p03;
    B0.h[0] = (__bf16)p10; B0.h[1] = (__bf16)p11;
    B1.h[0] = (__bf16)p12; B1.h[1] = (__bf16)p13;
    unsigned a0s = __shfl_xor(A0.u, 16), a1s = __shfl_xor(A1.u, 16);
    unsigned b0s = __shfl_xor(B0.u, 16), b1s = __shfl_xor(B1.u, 16);
    bool lo = (lg & 1) != 0, hi = (lg & 2) != 0;
    unsigned FA0 = lo ? a0s : A0.u, FA1 = lo ? a1s : A1.u;
    unsigned FA2 = lo ? A0.u : a0s, FA3 = lo ? A1.u : a1s;
    unsigned FB0 = lo ? b0s : B0.u, FB1 = lo ? b1s : B1.u;
    unsigned FB2 = lo ? B0.u : b0s, FB3 = lo ? B1.u : b1s;
    unsigned R0 = __shfl_xor(hi ? FA0 : FB0, 32);
    unsigned R1 = __shfl_xor(hi ? FA1 : FB1, 32);
    unsigned R2 = __shfl_xor(hi ? FA2 : FB2, 32);
    unsigned R3 = __shfl_xor(hi ? FA3 : FB3, 32);
    bool mid = lo != hi;
    union Fr { unsigned u[4]; bf16x8 v; } pa_u;
    pa_u.u[0] = mid ? R0 : (hi ? FB0 : FA0);
    pa_u.u[1] = mid ? R1 : (hi ? FB1 : FA1);
    pa_u.u[2] = mid ? R2 : (hi ? FB2 : FA2);
    pa_u.u[3] = mid ? R3 : (hi ? FB3 : FA3);
    bf16x8 pa = pa_u.v;

    __builtin_amdgcn_s_setprio(1);
#pragma unroll
    for (int dj = 0; dj < 16; dj++) {
      int d = dj * 16 + lr;
      int rr = d >> 1;
      int cp = (((d & 1) << 2) | lg) ^ (rr & 7);
      bf16x8 vf = *(const bf16x8*)(sV[cur] + rr * 64 + (cp << 3));
      o[dj] = __builtin_amdgcn_mfma_f32_16x16x32_bf16(pa, vf, o[dj], 0, 0, 0);
    }
    __builtin_amdgcn_s_setprio(0);
  }

  l_run += __shfl_xor(l_run, 16);
  l_run += __shfl_xor(l_run, 32);
  float i0 = 1.0f / __shfl(l_run, lg * 4 + 0);
  float i1 = 1.0f / __shfl(l_run, lg * 4 + 1);
  float i2 = 1.0f / __shfl(l_run, lg * 4 + 2);
  float i3 = 1.0f / __shfl(l_run, lg * 4 + 3);

  float* orow = out + (size_t)(b * 2048 + q0 + w * 16 + lg * 4) * 512 + d0;
#pragma unroll
  for (int dj = 0; dj < 16; dj++) {
    orow[(size_t)0 * 512 + dj * 16 + lr] = o[dj][0] * i0;
    orow[(size_t)1 * 512 + dj * 16 + lr] = o[dj][1] * i1;
    orow[(size_t)2 * 512 + dj * 16 + lr] = o[dj][2] * i2;
    orow[(size_t)3 * 512 + dj * 16 + lr] = o[dj][3] * i3;
  }
}

extern "C" void kernel_launch(void* const* d_in, const int* in_sizes, int n_in,
                              void* d_out, int out_size, void* d_ws, size_t ws_size,
                              hipStream_t stream) {
  (void)in_sizes; (void)n_in; (void)out_size;
  const float* x = (const float*)d_in[0];
  const float* Wq = (const float*)d_in[1];
  const float* bq = (const float*)d_in[2];
  const float* Wk = (const float*)d_in[3];
  const float* bk = (const float*)d_in[4];
  const float* Wv = (const float*)d_in[5];
  const float* bv = (const float*)d_in[6];
  float* out = (float*)d_out;
  char* ws = (char*)d_ws;

  const size_t NEED = 136052736;
  if (ws_size >= NEED) {
    __bf16* P = (__bf16*)(ws);
    __bf16* Qb = (__bf16*)(ws + 67108864);
    __bf16* Kb = (__bf16*)(ws + 83886080);
    __bf16* Vt = (__bf16*)(ws + 100663296);
    __bf16* Wt = (__bf16*)(ws + 134217728);
    float* lbuf = (float*)(ws + 135790592);

    k_wt<<<dim3(16, 16, 3), 256, 0, stream>>>(Wq, Wk, Wv, Wt);
    k_gemm<<<1536, 256, 0, stream>>>(x, Wt, bq, bk, bv, Qb, Kb, Vt);
    k_qk<<<512, 256, 0, stream>>>(Qb, Kb, P, lbuf);
    k_pv<<<1024, 256, 0, stream>>>(P, Vt, lbuf, out);
  } else {
    __bf16* Qb = (__bf16*)(ws + 16777216);
    __bf16* Kb = (__bf16*)(ws + 33554432);
    __bf16* Vt = (__bf16*)(ws + 50331648);
    __bf16* Wt = (__bf16*)(ws + 67108864);

    k_wt<<<dim3(16, 16, 3), 256, 0, stream>>>(Wq, Wk, Wv, Wt);
    k_gemm<<<1536, 256, 0, stream>>>(x, Wt, bq, bk, bv, Qb, Kb, Vt);
    k_fa<<<512, 256, 0, stream>>>(Qb, Kb, Vt, out);
  }
}

// Round 25
// 140.791 us; speedup vs baseline: 1.0392x; 1.0392x over previous
//
#include <hip/hip_runtime.h>

// B=8, N=2048, D_IN=D_OUT=512. out fp32 [8,2048,512].
// BIG-WS layout (needs >=136052736 B): P@0 (64M), Qb@64M, Kb@80M, Vt@96M,
// Wt@128M, lbuf@129.5M. FALLBACK: Qb@16M, Kb@32M, Vt@48M, Wt@64M.
// Round-25 = round-23 verified configuration (141.3us, absmax 0.00244),
// re-banked after round-24's pv 8-way dh-split regressed (+5us: P read
// duplication not L2-absorbed). Session floor.

typedef __bf16 bf16x8 __attribute__((ext_vector_type(8)));
typedef float f32x4 __attribute__((ext_vector_type(4)));
typedef float f32x16 __attribute__((ext_vector_type(16)));

#define AS1G __attribute__((address_space(1)))
#define AS3L __attribute__((address_space(3)))

__device__ __forceinline__ void gload16(const void* g, void* l) {
  __builtin_amdgcn_global_load_lds((const AS1G void*)g, (AS3L void*)l, 16, 0, 0);
}

// ---------------- W [d][e] fp32 -> Wt [z][e][d] bf16 ----------------
__global__ __launch_bounds__(256) void k_wt(const float* __restrict__ Wq, const float* __restrict__ Wk,
                                            const float* __restrict__ Wv, __bf16* __restrict__ Wt) {
  __shared__ float t[32][33];
  int z = blockIdx.z;
  const float* W = (z == 0) ? Wq : (z == 1 ? Wk : Wv);
  int r0 = blockIdx.y * 32, c0 = blockIdx.x * 32;
  int tr = threadIdx.x >> 5, tc = threadIdx.x & 31;
#pragma unroll
  for (int p = 0; p < 4; p++)
    t[tr + p * 8][tc] = W[(size_t)(r0 + tr + p * 8) * 512 + c0 + tc];
  __syncthreads();
#pragma unroll
  for (int p = 0; p < 4; p++)
    Wt[(size_t)z * 262144 + (size_t)(c0 + tr + p * 8) * 512 + r0 + tc] = (__bf16)t[tc][tr + p * 8];
}

// ---------------- fused QKV GEMM (x fp32 read + convert fused) ----------------
// A staged as FP32 from x directly (sA 32KB), converted to bf16 at fragment
// load. sA chunk swizzle: dest chunk d holds source chunk d ^ (2*((row>>1)&7));
// fragment (m = kc*4+lg) reads dest chunks 2(m^r3), 2(m^r3)+1 — 32B contiguous.
// XCD panel clustering (round-19-verified: FETCH 99.9->33MB): panel =
// (blk>>3)/12*8 + (blk&7); j = (blk>>3)%12 -> (e0, z).
__global__ __launch_bounds__(256) void k_gemm(const float* __restrict__ x, const __bf16* __restrict__ Wt,
                                              const float* __restrict__ bq, const float* __restrict__ bk,
                                              const float* __restrict__ bv,
                                              __bf16* __restrict__ Qb, __bf16* __restrict__ Kb,
                                              __bf16* __restrict__ Vt) {
  __shared__ float sA[128 * 64];
  __shared__ __bf16 sB[128 * 64];
  int blk = blockIdx.x;
  int xcd = blk & 7;
  int within = blk >> 3;
  int ph = within / 12;
  int j = within - ph * 12;
  int m0 = (ph * 8 + xcd) * 128;
  int e0 = (j & 3) * 128;
  int z = j >> 2;
  int tid = threadIdx.x, w = tid >> 6, l = tid & 63;
  int lr = l & 15, lg = l >> 4;
  int wm = (w & 1) * 64, wn = (w >> 1) * 64;
  const float* bias = (z == 0) ? bq : (z == 1 ? bk : bv);
  const __bf16* Wz = Wt + (size_t)z * 262144;

  float bval[4];
#pragma unroll
  for (int fn = 0; fn < 4; fn++) bval[fn] = bias[e0 + wn + fn * 16 + lr];

  f32x4 zero4 = {0.f, 0.f, 0.f, 0.f};
  f32x4 acc[4][4];
#pragma unroll
  for (int fm = 0; fm < 4; fm++)
#pragma unroll
    for (int fn = 0; fn < 4; fn++) acc[fm][fn] = zero4;

#pragma unroll 1
  for (int kt = 0; kt < 8; kt++) {
#pragma unroll
    for (int ii = 0; ii < 8; ii++) {
      int R0 = w * 32 + ii * 4;
      int row = R0 + (l >> 4);
      int cs = (l & 15) ^ ((2 * (row >> 1)) & 15);
      gload16(x + (size_t)(m0 + row) * 512 + kt * 64 + cs * 4, sA + R0 * 64);
    }
#pragma unroll
    for (int ii = 0; ii < 4; ii++) {
      int rt = (w * 4 + ii) * 8 + (l >> 3);
      int sw = ((l & 7) ^ (l >> 3)) << 3;
      gload16(Wz + (size_t)(e0 + rt) * 512 + kt * 64 + sw, sB + (w * 4 + ii) * 512);
    }
    __syncthreads();
#pragma unroll
    for (int kc = 0; kc < 2; kc++) {
      bf16x8 af[4], bfr[4];
#pragma unroll
      for (int f = 0; f < 4; f++) {
        int ra = wm + f * 16 + lr;
        int m = kc * 4 + lg;
        int pos = 2 * (m ^ ((ra >> 1) & 7));
        const float* pA = sA + ra * 64 + pos * 4;
        f32x4 a0 = *(const f32x4*)(pA);
        f32x4 a1 = *(const f32x4*)(pA + 4);
        bf16x8 av;
        av[0] = (__bf16)a0[0]; av[1] = (__bf16)a0[1]; av[2] = (__bf16)a0[2]; av[3] = (__bf16)a0[3];
        av[4] = (__bf16)a1[0]; av[5] = (__bf16)a1[1]; av[6] = (__bf16)a1[2]; av[7] = (__bf16)a1[3];
        af[f] = av;
        int rb = wn + f * 16 + lr;
        bfr[f] = *(const bf16x8*)(sB + rb * 64 + (((kc * 4 + lg) ^ (rb & 7)) << 3));
      }
#pragma unroll
      for (int fm = 0; fm < 4; fm++)
#pragma unroll
        for (int fn = 0; fn < 4; fn++)
          acc[fm][fn] = __builtin_amdgcn_mfma_f32_16x16x32_bf16(af[fm], bfr[fn], acc[fm][fn], 0, 0, 0);
    }
    __syncthreads();
  }

  if (z == 2) {
    int bb = m0 >> 11;
#pragma unroll
    for (int fm = 0; fm < 4; fm++) {
      int nl = (m0 & 2047) + wm + fm * 16 + lg * 4;
#pragma unroll
      for (int fn = 0; fn < 4; fn++) {
        alignas(8) __bf16 tmp[4];
#pragma unroll
        for (int r = 0; r < 4; r++) tmp[r] = (__bf16)(acc[fm][fn][r] + bval[fn]);
        *(float2*)(Vt + (size_t)bb * 1048576 + (size_t)(e0 + wn + fn * 16 + lr) * 2048 + nl) =
            *(float2*)tmp;
      }
    }
  } else {
    __bf16* dst = (z == 0) ? Qb : Kb;
    const float qmul = (z == 0) ? (1.4426950408889634f * 0.044194173824159216f) : 1.0f;
#pragma unroll
    for (int fm = 0; fm < 4; fm++)
#pragma unroll
      for (int fn = 0; fn < 4; fn++)
#pragma unroll
        for (int r = 0; r < 4; r++) {
          float v = (acc[fm][fn][r] + bval[fn]) * qmul;
          dst[(size_t)(m0 + wm + fm * 16 + lg * 4 + r) * 512 + e0 + wn + fn * 16 + lr] = (__bf16)v;
        }
  }
}

// ================= TWO-PASS PATH (big ws) =================
// No-max softmax (|s|<=36, round-12-proven): P-tiles directly summable. QK once,
// P (bf16 A-frags, 64MB) in ws, PV reads P from global. Both 32x32x16 MFMA.
// P byte addr: ((((b*16+qt)*64 + kvt)*2 + s2)*256 + tid)*16.

// k_qk: grid 512 = 8b x 16qt x 4kvh. 4 waves x 32 q-rows; kv quarter (512), 16 iters.
__global__ __launch_bounds__(256, 1) void k_qk(const __bf16* __restrict__ Qb, const __bf16* __restrict__ Kb,
                                               __bf16* __restrict__ P, float* __restrict__ lbuf) {
  __shared__ __bf16 sK[2][32 * 512];  // dbuf, XOR-8 16B-chunk swizzle per row

  int tid = threadIdx.x;
  int w = tid >> 6, l = tid & 63;
  int q32 = l & 31, hi = l >> 5;

  int blk = blockIdx.x;
  int b = blk & 7;
  int qt = (blk >> 3) & 15;
  int kvh = blk >> 7;

  const __bf16* Kbase = Kb + (size_t)b * 2048 * 512 + (size_t)kvh * 512 * 512;

  bf16x8 qf[32];
  const __bf16* qrow = Qb + (size_t)(b * 2048 + qt * 128 + w * 32 + q32) * 512 + hi * 8;
#pragma unroll
  for (int ks = 0; ks < 32; ks++) qf[ks] = *(const bf16x8*)(qrow + ks * 16);

  float l_run = 0.f;

#pragma unroll
  for (int i = 0; i < 8; i++) {
    int row = w * 8 + i;
    gload16(Kbase + (size_t)row * 512 + ((l ^ i) << 3), sK[0] + row * 512);
  }

#pragma unroll 1
  for (int it = 0; it < 16; it++) {
    int cur = it & 1;
    __syncthreads();

    if (it < 15) {
#pragma unroll
      for (int i = 0; i < 8; i++) {
        int row = w * 8 + i;
        gload16(Kbase + (size_t)((it + 1) * 32 + row) * 512 + ((l ^ i) << 3),
                sK[cur ^ 1] + row * 512);
      }
    }

    f32x16 s;
#pragma unroll
    for (int r = 0; r < 16; r++) s[r] = 0.f;
    __builtin_amdgcn_s_setprio(1);
#pragma unroll
    for (int ks = 0; ks < 32; ks++) {
      int c0 = 2 * ks + hi;
      bf16x8 kf = *(const bf16x8*)(sK[cur] + q32 * 512 + ((c0 ^ (q32 & 7)) << 3));
      s = __builtin_amdgcn_mfma_f32_32x32x16_bf16(kf, qf[ks], s, 0, 0, 0);
    }
    __builtin_amdgcn_s_setprio(0);

    union Pk { unsigned u; __bf16 h[2]; };
    unsigned pk[4][2];
    float ps = 0.f;
#pragma unroll
    for (int g = 0; g < 4; g++) {
      float p0 = exp2f(s[4 * g + 0]), p1 = exp2f(s[4 * g + 1]);
      float p2 = exp2f(s[4 * g + 2]), p3 = exp2f(s[4 * g + 3]);
      ps += (p0 + p1) + (p2 + p3);
      Pk t0; t0.h[0] = (__bf16)p0; t0.h[1] = (__bf16)p1; pk[g][0] = t0.u;
      Pk t1; t1.h[0] = (__bf16)p2; t1.h[1] = (__bf16)p3; pk[g][1] = t1.u;
    }
    l_run += ps;

    int kvt = kvh * 16 + it;
    size_t pbase = (((size_t)(b * 16 + qt) * 64 + kvt) * 2) * 256 + tid;
#pragma unroll
    for (int s2 = 0; s2 < 2; s2++) {
      unsigned snd0 = hi ? pk[2 * s2][0] : pk[2 * s2 + 1][0];
      unsigned snd1 = hi ? pk[2 * s2][1] : pk[2 * s2 + 1][1];
      unsigned rc0 = __shfl_xor(snd0, 32);
      unsigned rc1 = __shfl_xor(snd1, 32);
      union Fr { unsigned u[4]; f32x4 f; } fu;
      fu.u[0] = hi ? rc0 : pk[2 * s2][0];
      fu.u[1] = hi ? rc1 : pk[2 * s2][1];
      fu.u[2] = hi ? pk[2 * s2 + 1][0] : rc0;
      fu.u[3] = hi ? pk[2 * s2 + 1][1] : rc1;
      ((f32x4*)P)[pbase + (size_t)s2 * 256] = fu.f;
    }
  }

  l_run += __shfl_xor(l_run, 32);
  if (hi == 0)
    lbuf[(size_t)(b * 4 + kvh) * 2048 + qt * 128 + w * 32 + q32] = l_run;
}

// k_pv: grid 512 = 8b x 16qt x 4dh. 4 waves x 32 q-rows x 128 d-cols; 64 kv-tiles.
__global__ __launch_bounds__(256, 2) void k_pv(const __bf16* __restrict__ P, const __bf16* __restrict__ Vt,
                                               const float* __restrict__ lbuf, float* __restrict__ out) {
  __shared__ __bf16 sV[2][64 * 64];

  int tid = threadIdx.x;
  int w = tid >> 6, l = tid & 63;
  int q32 = l & 31, hi = l >> 5;

  int blk = blockIdx.x;
  int b = blk & 7;
  int qt = (blk >> 3) & 15;
  int d0 = (blk >> 7) * 128;

  const __bf16* Vbase = Vt + (size_t)b * 512 * 2048 + (size_t)d0 * 2048;

  f32x16 o[4];
#pragma unroll
  for (int dt = 0; dt < 4; dt++)
#pragma unroll
    for (int r = 0; r < 16; r++) o[dt][r] = 0.f;

#pragma unroll
  for (int i = 0; i < 2; i++) {
    int rr = (w * 2 + i) * 8 + (l >> 3);
    int cl = (l & 7) ^ (l >> 3);
    gload16(Vbase + (size_t)(2 * rr + (cl >> 2)) * 2048 + ((cl & 3) << 3),
            sV[0] + (w * 2 + i) * 512);
  }

  size_t pbase0 = ((size_t)(b * 16 + qt) * 64) * 2 * 256 + tid;
  union Fr { f32x4 f; bf16x8 h; };
  Fr u0, u1, n0, n1, m0, m1;
  u0.f = ((const f32x4*)P)[pbase0];
  u1.f = ((const f32x4*)P)[pbase0 + 256];
  n0.f = ((const f32x4*)P)[pbase0 + 512];
  n1.f = ((const f32x4*)P)[pbase0 + 512 + 256];

#pragma unroll 1
  for (int kvt = 0; kvt < 64; kvt++) {
    int cur = kvt & 1;
    __syncthreads();

    if (kvt < 63) {
#pragma unroll
      for (int i = 0; i < 2; i++) {
        int rr = (w * 2 + i) * 8 + (l >> 3);
        int cl = (l & 7) ^ (l >> 3);
        gload16(Vbase + (size_t)(2 * rr + (cl >> 2)) * 2048 + (kvt + 1) * 32 + ((cl & 3) << 3),
                sV[cur ^ 1] + (w * 2 + i) * 512);
      }
    }
    if (kvt < 62) {
      m0.f = ((const f32x4*)P)[pbase0 + (size_t)(kvt + 2) * 512];
      m1.f = ((const f32x4*)P)[pbase0 + (size_t)(kvt + 2) * 512 + 256];
    }

    __builtin_amdgcn_s_setprio(1);
#pragma unroll
    for (int dt = 0; dt < 4; dt++) {
      int dd = dt * 32 + q32;
      int rr = dd >> 1;
      int cp0 = (((dd & 1) << 2) | hi) ^ (rr & 7);
      bf16x8 vf0 = *(const bf16x8*)(sV[cur] + rr * 64 + (cp0 << 3));
      o[dt] = __builtin_amdgcn_mfma_f32_32x32x16_bf16(u0.h, vf0, o[dt], 0, 0, 0);
      int cp1 = (((dd & 1) << 2) | (2 + hi)) ^ (rr & 7);
      bf16x8 vf1 = *(const bf16x8*)(sV[cur] + rr * 64 + (cp1 << 3));
      o[dt] = __builtin_amdgcn_mfma_f32_32x32x16_bf16(u1.h, vf1, o[dt], 0, 0, 0);
    }
    __builtin_amdgcn_s_setprio(0);
    u0 = n0; u1 = n1;
    n0 = m0; n1 = m1;
  }

  float L = 0.f;
  const float* lb = lbuf + (size_t)b * 4 * 2048 + qt * 128 + w * 32 + q32;
#pragma unroll
  for (int kvh = 0; kvh < 4; kvh++) L += lb[(size_t)kvh * 2048];

  float* obase = out + (size_t)(b * 2048 + qt * 128 + w * 32) * 512 + d0;
#pragma unroll
  for (int r = 0; r < 16; r++) {
    int q = (r & 3) + 8 * (r >> 2) + 4 * hi;
    float iv = 1.0f / __shfl(L, q);
#pragma unroll
    for (int dt = 0; dt < 4; dt++)
      obase[(size_t)q * 512 + dt * 32 + q32] = o[dt][r] * iv;
  }
}

// ================= FALLBACK (round-14 k_fa) =================
__global__ __launch_bounds__(256, 2) void k_fa(const __bf16* __restrict__ Qb, const __bf16* __restrict__ Kb,
                                               const __bf16* __restrict__ Vt, float* __restrict__ out) {
  __shared__ __bf16 sK[32 * 512];
  __shared__ __bf16 sV[2][128 * 64];

  int tid = threadIdx.x;
  int w = tid >> 6, l = tid & 63;
  int lr = l & 15, lg = l >> 4;

  int blk = blockIdx.x;
  int b = blk & 7;
  int q0 = ((blk >> 3) & 31) * 64;
  int d0 = (blk >> 8) * 256;

  const __bf16* Kbase = Kb + (size_t)b * 2048 * 512;
  const __bf16* Vbase = Vt + (size_t)b * 512 * 2048 + (size_t)d0 * 2048;

  bf16x8 qf[16];
  const __bf16* qrow = Qb + (size_t)(b * 2048 + q0 + w * 16 + lr) * 512;
#pragma unroll
  for (int dk = 0; dk < 16; dk++) qf[dk] = *(const bf16x8*)(qrow + dk * 32 + lg * 8);

  f32x4 zero4 = {0.f, 0.f, 0.f, 0.f};
  f32x4 o[16];
#pragma unroll
  for (int dj = 0; dj < 16; dj++) o[dj] = zero4;
  float l_run = 0.f;

#pragma unroll
  for (int i = 0; i < 8; i++) {
    int row = w * 8 + i;
    gload16(Kbase + (size_t)row * 512 + ((l ^ i) << 3), sK + row * 512);
  }
#pragma unroll
  for (int i = 0; i < 4; i++) {
    int rr = (w * 4 + i) * 8 + (l >> 3);
    int cl = (l & 7) ^ (l >> 3);
    gload16(Vbase + (size_t)(2 * rr + (cl >> 2)) * 2048 + ((cl & 3) << 3),
            sV[0] + (w * 4 + i) * 512);
  }

#pragma unroll 1
  for (int it = 0; it < 64; it++) {
    int cur = it & 1;
    __syncthreads();

    f32x4 s[2] = {zero4, zero4};
    __builtin_amdgcn_s_setprio(1);
#pragma unroll
    for (int dk = 0; dk < 16; dk++) {
#pragma unroll
      for (int j = 0; j < 2; j++) {
        int row = j * 16 + lr;
        bf16x8 kf = *(const bf16x8*)(sK + row * 512 + (((dk * 4 + lg) ^ (lr & 7)) << 3));
        s[j] = __builtin_amdgcn_mfma_f32_16x16x32_bf16(kf, qf[dk], s[j], 0, 0, 0);
      }
    }
    __builtin_amdgcn_s_setprio(0);
    __syncthreads();

    if (it < 63) {
      int kvn = (it + 1) * 32;
#pragma unroll
      for (int i = 0; i < 8; i++) {
        int row = w * 8 + i;
        gload16(Kbase + (size_t)(kvn + row) * 512 + ((l ^ i) << 3), sK + row * 512);
      }
#pragma unroll
      for (int i = 0; i < 4; i++) {
        int rr = (w * 4 + i) * 8 + (l >> 3);
        int cl = (l & 7) ^ (l >> 3);
        gload16(Vbase + (size_t)(2 * rr + (cl >> 2)) * 2048 + kvn + ((cl & 3) << 3),
                sV[cur ^ 1] + (w * 4 + i) * 512);
      }
    }

    float p00 = exp2f(s[0][0]), p01 = exp2f(s[0][1]);
    float p02 = exp2f(s[0][2]), p03 = exp2f(s[0][3]);
    float p10 = exp2f(s[1][0]), p11 = exp2f(s[1][1]);
    float p12 = exp2f(s[1][2]), p13 = exp2f(s[1][3]);
    l_run += ((p00 + p01) + (p02 + p03)) + ((p10 + p11) + (p12 + p13));

    union Pk { unsigned u; __bf16 h[2]; };
    Pk A0, A1, B0, B1;
    A0.h[0] = (__bf16)p00; A0.h[1] = (__bf16)p01;
    A1.h[0] = (__bf16)p02; A1.h[1] = (__bf16)p03;
    B0.h[0] = (__bf16)p10; B0.h[1] = (__bf16)p11;
    B1.h[0] = (__bf16)p12; B1.h[1] = (__bf16)p13;
    unsigned a0s = __shfl_xor(A0.u, 16), a1s = __shfl_xor(A1.u, 16);
    unsigned b0s = __shfl_xor(B0.u, 16), b1s = __shfl_xor(B1.u, 16);
    bool lo = (lg & 1) != 0, hi = (lg & 2) != 0;
    unsigned FA0 = lo ? a0s : A0.u, FA1 = lo ? a1s : A1.u;
    unsigned FA2 = lo ? A0.u : a0s, FA3 = lo ? A1.u : a1s;
    unsigned FB0 = lo ? b0s : B0.u, FB1 = lo ? b1s : B1.u;
    unsigned FB2 = lo ? B0.u : b0s, FB3 = lo ? B1.u : b1s;
    unsigned R0 = __shfl_xor(hi ? FA0 : FB0, 32);
    unsigned R1 = __shfl_xor(hi ? FA1 : FB1, 32);
    unsigned R2 = __shfl_xor(hi ? FA2 : FB2, 32);
    unsigned R3 = __shfl_xor(hi ? FA3 : FB3, 32);
    bool mid = lo != hi;
    union Fr { unsigned u[4]; bf16x8 v; } pa_u;
    pa_u.u[0] = mid ? R0 : (hi ? FB0 : FA0);
    pa_u.u[1] = mid ? R1 : (hi ? FB1 : FA1);
    pa_u.u[2] = mid ? R2 : (hi ? FB2 : FA2);
    pa_u.u[3] = mid ? R3 : (hi ? FB3 : FA3);
    bf16x8 pa = pa_u.v;

    __builtin_amdgcn_s_setprio(1);
#pragma unroll
    for (int dj = 0; dj < 16; dj++) {
      int d = dj * 16 + lr;
      int rr = d >> 1;
      int cp = (((d & 1) << 2) | lg) ^ (rr & 7);
      bf16x8 vf = *(const bf16x8*)(sV[cur] + rr * 64 + (cp << 3));
      o[dj] = __builtin_amdgcn_mfma_f32_16x16x32_bf16(pa, vf, o[dj], 0, 0, 0);
    }
    __builtin_amdgcn_s_setprio(0);
  }

  l_run += __shfl_xor(l_run, 16);
  l_run += __shfl_xor(l_run, 32);
  float i0 = 1.0f / __shfl(l_run, lg * 4 + 0);
  float i1 = 1.0f / __shfl(l_run, lg * 4 + 1);
  float i2 = 1.0f / __shfl(l_run, lg * 4 + 2);
  float i3 = 1.0f / __shfl(l_run, lg * 4 + 3);

  float* orow = out + (size_t)(b * 2048 + q0 + w * 16 + lg * 4) * 512 + d0;
#pragma unroll
  for (int dj = 0; dj < 16; dj++) {
    orow[(size_t)0 * 512 + dj * 16 + lr] = o[dj][0] * i0;
    orow[(size_t)1 * 512 + dj * 16 + lr] = o[dj][1] * i1;
    orow[(size_t)2 * 512 + dj * 16 + lr] = o[dj][2] * i2;
    orow[(size_t)3 * 512 + dj * 16 + lr] = o[dj][3] * i3;
  }
}

extern "C" void kernel_launch(void* const* d_in, const int* in_sizes, int n_in,
                              void* d_out, int out_size, void* d_ws, size_t ws_size,
                              hipStream_t stream) {
  (void)in_sizes; (void)n_in; (void)out_size;
  const float* x = (const float*)d_in[0];
  const float* Wq = (const float*)d_in[1];
  const float* bq = (const float*)d_in[2];
  const float* Wk = (const float*)d_in[3];
  const float* bk = (const float*)d_in[4];
  const float* Wv = (const float*)d_in[5];
  const float* bv = (const float*)d_in[6];
  float* out = (float*)d_out;
  char* ws = (char*)d_ws;

  const size_t NEED = 136052736;
  if (ws_size >= NEED) {
    __bf16* P = (__bf16*)(ws);
    __bf16* Qb = (__bf16*)(ws + 67108864);
    __bf16* Kb = (__bf16*)(ws + 83886080);
    __bf16* Vt = (__bf16*)(ws + 100663296);
    __bf16* Wt = (__bf16*)(ws + 134217728);
    float* lbuf = (float*)(ws + 135790592);

    k_wt<<<dim3(16, 16, 3), 256, 0, stream>>>(Wq, Wk, Wv, Wt);
    k_gemm<<<1536, 256, 0, stream>>>(x, Wt, bq, bk, bv, Qb, Kb, Vt);
    k_qk<<<512, 256, 0, stream>>>(Qb, Kb, P, lbuf);
    k_pv<<<512, 256, 0, stream>>>(P, Vt, lbuf, out);
  } else {
    __bf16* Qb = (__bf16*)(ws + 16777216);
    __bf16* Kb = (__bf16*)(ws + 33554432);
    __bf16* Vt = (__bf16*)(ws + 50331648);
    __bf16* Wt = (__bf16*)(ws + 67108864);

    k_wt<<<dim3(16, 16, 3), 256, 0, stream>>>(Wq, Wk, Wv, Wt);
    k_gemm<<<1536, 256, 0, stream>>>(x, Wt, bq, bk, bv, Qb, Kb, Vt);
    k_fa<<<512, 256, 0, stream>>>(Qb, Kb, Vt, out);
  }
}